// Round 1
// baseline (254.132 us; speedup 1.0000x reference)
//
#include <hip/hip_runtime.h>
#include <hip/hip_bf16.h>

#define NREV 500000
#define DIM  128
#define KDIM 384

typedef __attribute__((ext_vector_type(4))) float f32x4;
typedef __attribute__((ext_vector_type(8))) short bf16x8;

__device__ __forceinline__ unsigned short f2bf(float x) {
    // round-to-nearest-even f32 -> bf16 (inputs are finite)
    unsigned int u = __builtin_bit_cast(unsigned int, x);
    u = (u + 0x7FFFu + ((u >> 16) & 1u)) >> 16;
    return (unsigned short)u;
}

// Convert W [384][128] f32 -> Bt [128][384] bf16 (transposed) in workspace.
// Bt[n][k] = bf16(W[k][n]); lane's B-fragment is then 16B contiguous.
__global__ void wconv_kernel(const float* __restrict__ W,
                             unsigned short* __restrict__ Bt) {
    int t = blockIdx.x * 256 + threadIdx.x;
    if (t < KDIM * DIM) {
        int k = t >> 7;    // 0..383
        int n = t & 127;   // 0..127
        Bt[n * KDIM + k] = f2bf(W[t]);
    }
}

// Fused gather + GEMM + ReLU.
// Block: 128 reviews x 128 out-cols, 4 waves (each 64x64), K=384 in 6 steps of 64.
// K-steps 0-1: review rows (direct), 2-3: user gather, 4-5: item gather.
__global__ __launch_bounds__(256, 2) void agg_kernel(
    const float* __restrict__ rev,
    const float* __restrict__ item,
    const float* __restrict__ user,
    const int*   __restrict__ uidx,
    const int*   __restrict__ iidx,
    const unsigned short* __restrict__ Bt,
    float* __restrict__ out)
{
    // A-tile: 128 rows x 64 cols bf16, XOR-swizzled (byte ^= (row&7)<<4)
    __shared__ unsigned short Asm[128 * 64];
    __shared__ int su[128];
    __shared__ int si[128];

    const int r0 = blockIdx.x * 128;
    const int t  = threadIdx.x;

    if (t < 128) {
        int gr = r0 + t;
        if (gr >= NREV) gr = NREV - 1;   // clamp tail; stores predicated below
        su[t] = uidx[gr];
        si[t] = iidx[gr];
    }
    __syncthreads();

    const int wid  = t >> 6;        // 0..3
    const int lane = t & 63;
    const int wr   = wid >> 1;      // 0..1 : row half
    const int wc   = wid & 1;       // 0..1 : col half
    const int lm   = lane & 15;     // frag row (A) / frag col (B/C)
    const int lk   = lane >> 4;     // k-group 0..3

    f32x4 acc[4][4];
    #pragma unroll
    for (int i = 0; i < 4; ++i)
        #pragma unroll
        for (int j = 0; j < 4; ++j)
            acc[i][j] = (f32x4){0.f, 0.f, 0.f, 0.f};

    char* lds = reinterpret_cast<char*>(Asm);
    const int c4 = (t & 15) * 4;    // 4 f32 columns per thread per row-chunk

    for (int ks = 0; ks < 6; ++ks) {
        // ---- stage A-tile: rows 0..127, cols ks*64..ks*64+63 -> bf16 swizzled LDS
        #pragma unroll
        for (int it = 0; it < 8; ++it) {
            int r = (t >> 4) + 16 * it;          // 0..127
            const float* src;
            if (ks < 2) {
                int gr = r0 + r;
                if (gr >= NREV) gr = NREV - 1;
                src = rev + (size_t)gr * DIM + ks * 64;
            } else if (ks < 4) {
                src = user + (size_t)su[r] * DIM + (ks - 2) * 64;
            } else {
                src = item + (size_t)si[r] * DIM + (ks - 4) * 64;
            }
            float4 v = *reinterpret_cast<const float4*>(src + c4);
            unsigned int lo = (unsigned int)f2bf(v.x) | ((unsigned int)f2bf(v.y) << 16);
            unsigned int hi = (unsigned int)f2bf(v.z) | ((unsigned int)f2bf(v.w) << 16);
            int byte = r * 128 + c4 * 2;
            byte ^= (r & 7) << 4;                // swizzle
            uint2 pk; pk.x = lo; pk.y = hi;
            *reinterpret_cast<uint2*>(lds + byte) = pk;
        }
        __syncthreads();

        // ---- B fragments direct from global Bt (L2-resident 98KB)
        bf16x8 bfrag[2][4];
        const int kb = ks * 64;
        #pragma unroll
        for (int kk = 0; kk < 2; ++kk)
            #pragma unroll
            for (int nf = 0; nf < 4; ++nf) {
                int n = wc * 64 + nf * 16 + lm;
                int k = kb + kk * 32 + lk * 8;
                bfrag[kk][nf] = *reinterpret_cast<const bf16x8*>(Bt + n * KDIM + k);
            }

        // ---- A fragments from swizzled LDS
        bf16x8 afrag[2][4];
        #pragma unroll
        for (int kk = 0; kk < 2; ++kk)
            #pragma unroll
            for (int mf = 0; mf < 4; ++mf) {
                int r = wr * 64 + mf * 16 + lm;
                int byte = r * 128 + kk * 64 + lk * 16;
                byte ^= (r & 7) << 4;
                afrag[kk][mf] = *reinterpret_cast<const bf16x8*>(lds + byte);
            }

        // ---- MFMA: 2 k-substeps x 4 m x 4 n
        #pragma unroll
        for (int kk = 0; kk < 2; ++kk)
            #pragma unroll
            for (int mf = 0; mf < 4; ++mf)
                #pragma unroll
                for (int nf = 0; nf < 4; ++nf)
                    acc[mf][nf] = __builtin_amdgcn_mfma_f32_16x16x32_bf16(
                        afrag[kk][mf], bfrag[kk][nf], acc[mf][nf], 0, 0, 0);

        __syncthreads();
    }

    // ---- epilogue: ReLU + f32 store (C/D layout: col=lane&15, row=(lane>>4)*4+j)
    #pragma unroll
    for (int mf = 0; mf < 4; ++mf) {
        #pragma unroll
        for (int j = 0; j < 4; ++j) {
            int row = r0 + wr * 64 + mf * 16 + lk * 4 + j;
            if (row < NREV) {
                float* orow = out + (size_t)row * DIM + wc * 64;
                #pragma unroll
                for (int nf = 0; nf < 4; ++nf)
                    orow[nf * 16 + lm] = fmaxf(acc[mf][nf][j], 0.0f);
            }
        }
    }
}

extern "C" void kernel_launch(void* const* d_in, const int* in_sizes, int n_in,
                              void* d_out, int out_size, void* d_ws, size_t ws_size,
                              hipStream_t stream) {
    const float* rev  = (const float*)d_in[0];
    const float* item = (const float*)d_in[1];
    const float* user = (const float*)d_in[2];
    const int*   uidx = (const int*)d_in[3];
    const int*   iidx = (const int*)d_in[4];
    const float* W    = (const float*)d_in[5];
    unsigned short* Bt = (unsigned short*)d_ws;   // 128*384*2 = 98304 B
    float* out = (float*)d_out;

    wconv_kernel<<<(KDIM * DIM + 255) / 256, 256, 0, stream>>>(W, Bt);

    int nblocks = (NREV + 127) / 128;   // 3907
    agg_kernel<<<nblocks, 256, 0, stream>>>(rev, item, user, uidx, iidx, Bt, out);
}

// Round 2
// 205.507 us; speedup vs baseline: 1.2366x; 1.2366x over previous
//
#include <hip/hip_runtime.h>
#include <hip/hip_bf16.h>

#define NREV 500000
#define DIM  128
#define KDIM 384

typedef __attribute__((ext_vector_type(4))) float f32x4;
typedef __attribute__((ext_vector_type(8))) short bf16x8;

__device__ __forceinline__ unsigned int f2bf(float x) {
    // round-to-nearest-even f32 -> bf16 (inputs are finite)
    unsigned int u = __builtin_bit_cast(unsigned int, x);
    u = (u + 0x7FFFu + ((u >> 16) & 1u)) >> 16;
    return u;
}

// Convert W [384][128] f32 -> Bt [128][384] bf16 (transposed) in workspace.
// Bt[n][k] = bf16(W[k][n]); lane's B-fragment is then 16B contiguous.
__global__ void wconv_kernel(const float* __restrict__ W,
                             unsigned short* __restrict__ Bt) {
    int t = blockIdx.x * 256 + threadIdx.x;
    if (t < KDIM * DIM) {
        int k = t >> 7;    // 0..383
        int n = t & 127;   // 0..127
        Bt[n * KDIM + k] = (unsigned short)f2bf(W[t]);
    }
}

// Fused gather + GEMM + ReLU.
// Block: 128 reviews x 128 out-cols, 4 waves (each 64x64), K=384 in 6 steps of 64.
// K-steps 0-1: review rows (direct), 2-3: user gather, 4-5: item gather.
// Double-buffered LDS A-tile; step ks+1 loads issued before step ks compute
// (issue-early / write-late), one barrier per K-step.
__global__ __launch_bounds__(256, 3) void agg_kernel(
    const float* __restrict__ rev,
    const float* __restrict__ item,
    const float* __restrict__ user,
    const int*   __restrict__ uidx,
    const int*   __restrict__ iidx,
    const unsigned short* __restrict__ Bt,
    float* __restrict__ out)
{
    // A-tile: 2 x (128 rows x 64 cols bf16), XOR-swizzled (byte ^= (row&7)<<4)
    __shared__ unsigned short Asm[2][128 * 64];
    __shared__ int su[128];
    __shared__ int si[128];

    const int r0 = blockIdx.x * 128;
    const int t  = threadIdx.x;

    if (t < 128) {
        int gr = r0 + t;
        if (gr >= NREV) gr = NREV - 1;   // clamp tail; stores predicated below
        su[t] = uidx[gr];
        si[t] = iidx[gr];
    }
    // no barrier needed yet: su/si first consumed in stage_load(2) (during
    // ks==1), which is after the prologue __syncthreads below.

    const int wid  = t >> 6;        // 0..3
    const int lane = t & 63;
    const int wr   = wid >> 1;      // 0..1 : row half
    const int wc   = wid & 1;       // 0..1 : col half
    const int lm   = lane & 15;     // frag row (A) / frag col (B/C)
    const int lk   = lane >> 4;     // k-group 0..3

    const int c4    = (t & 15) * 4; // 4 f32 columns per thread per row-chunk
    const int rbase = t >> 4;       // 0..15

    // global -> registers for one 128x64 A sub-tile (8 x float4 per thread)
    auto stage_load = [&](int ks, float4* stg) {
        #pragma unroll
        for (int it = 0; it < 8; ++it) {
            int r = rbase + 16 * it;             // 0..127
            const float* src;
            if (ks < 2) {
                int gr = r0 + r;
                if (gr >= NREV) gr = NREV - 1;
                src = rev + (size_t)gr * DIM + ks * 64;
            } else if (ks < 4) {
                src = user + (size_t)su[r] * DIM + (ks - 2) * 64;
            } else {
                src = item + (size_t)si[r] * DIM + (ks - 4) * 64;
            }
            stg[it] = *reinterpret_cast<const float4*>(src + c4);
        }
    };

    // registers -> bf16 swizzled LDS
    auto stage_write = [&](int buf, const float4* stg) {
        char* lds = reinterpret_cast<char*>(Asm[buf]);
        #pragma unroll
        for (int it = 0; it < 8; ++it) {
            int r = rbase + 16 * it;
            float4 v = stg[it];
            unsigned int lo = f2bf(v.x) | (f2bf(v.y) << 16);
            unsigned int hi = f2bf(v.z) | (f2bf(v.w) << 16);
            int byte = r * 128 + c4 * 2;
            byte ^= (r & 7) << 4;                // swizzle
            uint2 pk; pk.x = lo; pk.y = hi;
            *reinterpret_cast<uint2*>(lds + byte) = pk;
        }
    };

    f32x4 acc[4][4];
    #pragma unroll
    for (int i = 0; i < 4; ++i)
        #pragma unroll
        for (int j = 0; j < 4; ++j)
            acc[i][j] = (f32x4){0.f, 0.f, 0.f, 0.f};

    float4 stg[8];
    stage_load(0, stg);
    stage_write(0, stg);
    __syncthreads();

    for (int ks = 0; ks < 6; ++ks) {
        const int cur = ks & 1;

        // ---- issue next-step global loads first (latency hides under compute)
        if (ks < 5) stage_load(ks + 1, stg);

        // ---- B fragments direct from global Bt (L2-resident 98KB)
        bf16x8 bfrag[2][4];
        const int kb = ks * 64;
        #pragma unroll
        for (int kk = 0; kk < 2; ++kk)
            #pragma unroll
            for (int nf = 0; nf < 4; ++nf) {
                int n = wc * 64 + nf * 16 + lm;
                int k = kb + kk * 32 + lk * 8;
                bfrag[kk][nf] = *reinterpret_cast<const bf16x8*>(Bt + n * KDIM + k);
            }

        // ---- A fragments from swizzled LDS
        const char* lds = reinterpret_cast<const char*>(Asm[cur]);
        bf16x8 afrag[2][4];
        #pragma unroll
        for (int kk = 0; kk < 2; ++kk)
            #pragma unroll
            for (int mf = 0; mf < 4; ++mf) {
                int r = wr * 64 + mf * 16 + lm;
                int byte = r * 128 + kk * 64 + lk * 16;
                byte ^= (r & 7) << 4;
                afrag[kk][mf] = *reinterpret_cast<const bf16x8*>(lds + byte);
            }

        // ---- MFMA: 2 k-substeps x 4 m x 4 n
        #pragma unroll
        for (int kk = 0; kk < 2; ++kk)
            #pragma unroll
            for (int mf = 0; mf < 4; ++mf)
                #pragma unroll
                for (int nf = 0; nf < 4; ++nf)
                    acc[mf][nf] = __builtin_amdgcn_mfma_f32_16x16x32_bf16(
                        afrag[kk][mf], bfrag[kk][nf], acc[mf][nf], 0, 0, 0);

        // ---- write-late: next tile into the other buffer (safe: that buffer
        // was last read in step ks-1, sealed by the barrier below)
        if (ks < 5) stage_write(cur ^ 1, stg);
        __syncthreads();
    }

    // ---- epilogue: ReLU + f32 store (C/D layout: col=lane&15, row=(lane>>4)*4+j)
    #pragma unroll
    for (int mf = 0; mf < 4; ++mf) {
        #pragma unroll
        for (int j = 0; j < 4; ++j) {
            int row = r0 + wr * 64 + mf * 16 + lk * 4 + j;
            if (row < NREV) {
                float* orow = out + (size_t)row * DIM + wc * 64;
                #pragma unroll
                for (int nf = 0; nf < 4; ++nf)
                    orow[nf * 16 + lm] = fmaxf(acc[mf][nf][j], 0.0f);
            }
        }
    }
}

extern "C" void kernel_launch(void* const* d_in, const int* in_sizes, int n_in,
                              void* d_out, int out_size, void* d_ws, size_t ws_size,
                              hipStream_t stream) {
    const float* rev  = (const float*)d_in[0];
    const float* item = (const float*)d_in[1];
    const float* user = (const float*)d_in[2];
    const int*   uidx = (const int*)d_in[3];
    const int*   iidx = (const int*)d_in[4];
    const float* W    = (const float*)d_in[5];
    unsigned short* Bt = (unsigned short*)d_ws;   // 128*384*2 = 98304 B
    float* out = (float*)d_out;

    wconv_kernel<<<(KDIM * DIM + 255) / 256, 256, 0, stream>>>(W, Bt);

    int nblocks = (NREV + 127) / 128;   // 3907
    agg_kernel<<<nblocks, 256, 0, stream>>>(rev, item, user, uidx, iidx, Bt, out);
}

// Round 3
// 179.117 us; speedup vs baseline: 1.4188x; 1.1473x over previous
//
#include <hip/hip_runtime.h>
#include <hip/hip_bf16.h>

#define NREV 500000
#define DIM  128
#define KDIM 384

typedef __attribute__((ext_vector_type(4))) float f32x4;
typedef __attribute__((ext_vector_type(8))) short bf16x8;

__device__ __forceinline__ unsigned short f2bf_s(float x) {
    // round-to-nearest-even f32 -> bf16
    unsigned int u = __builtin_bit_cast(unsigned int, x);
    u = (u + 0x7FFFu + ((u >> 16) & 1u)) >> 16;
    return (unsigned short)u;
}

// W [384][128] f32 -> Bw frag-linear bf16:
// Bw[((ks*8+fg)*64 + l)*8 + j] = bf16( W[ks*32 + (l>>4)*8 + j][fg*16 + (l&15)] )
// so each lane's 16B B-fragment is contiguous and LDS staging is a linear copy.
__global__ void wconv_kernel(const float* __restrict__ W,
                             unsigned short* __restrict__ Bw) {
    int e = blockIdx.x * 256 + threadIdx.x;
    if (e < 12 * 8 * 64 * 8) {
        int j  = e & 7;
        int l  = (e >> 3) & 63;
        int fg = (e >> 9) & 7;
        int ks = e >> 12;
        int n = fg * 16 + (l & 15);
        int k = ks * 32 + ((l >> 4) << 3) + j;
        Bw[e] = f2bf_s(W[k * DIM + n]);
    }
}

__device__ __forceinline__ void gload_lds16(const void* g, void* l) {
    __builtin_amdgcn_global_load_lds(
        (const __attribute__((address_space(1))) void*)g,
        (__attribute__((address_space(3))) void*)l, 16, 0, 0);
}

// truncation-pack: two f32 -> one dword of two bf16 (cheap; threshold has margin)
__device__ __forceinline__ unsigned int pktrunc(float lo, float hi) {
    unsigned int a = __builtin_bit_cast(unsigned int, lo);
    unsigned int b = __builtin_bit_cast(unsigned int, hi);
    return (b & 0xFFFF0000u) | (a >> 16);
}
__device__ __forceinline__ bf16x8 cvt8(f32x4 a, f32x4 b) {
    union { bf16x8 v; unsigned int u[4]; } U;
    U.u[0] = pktrunc(a[0], a[1]);
    U.u[1] = pktrunc(a[2], a[3]);
    U.u[2] = pktrunc(b[0], b[1]);
    U.u[3] = pktrunc(b[2], b[3]);
    return U.v;
}

// Fused gather + GEMM + ReLU.
// Block: 128 rows x 128 cols, 4 waves (64x64 each). K=384 in 12 steps of 32.
// Steps 0-3: review, 4-7: user gather, 8-11: item gather.
// Triple-buffered LDS, 2-step-ahead global_load_lds prefetch, counted vmcnt(6),
// raw s_barrier (never drain the prefetch queue mid-loop).
__global__ __launch_bounds__(256, 2) void agg_kernel(
    const float* __restrict__ rev,
    const float* __restrict__ item,
    const float* __restrict__ user,
    const int*   __restrict__ uidx,
    const int*   __restrict__ iidx,
    const unsigned short* __restrict__ Bw,
    float* __restrict__ out)
{
    // A: f32 [128][32] per buffer, XOR-swizzled via pre-swizzled SOURCE cols
    // (global_load_lds dest must stay linear). B: bf16 frag-linear, 8KB/buffer.
    __shared__ __align__(16) float          Atile[3][128 * 32];
    __shared__ __align__(16) unsigned short Btile[3][4096];

    const int r0   = blockIdx.x * 128;
    const int t    = threadIdx.x;
    const int wid  = t >> 6, lane = t & 63;
    const int wr   = wid >> 1, wc = wid & 1;
    const int lm   = lane & 15, lk = lane >> 4;

    // staging geometry: thread t stages rows it*32+(t>>3), f32 cols (t&7)*4,
    // with source col pre-swizzled so LDS byte x of row r holds col (x ^ ((r&7)<<4))
    const int srow = t >> 3;
    const int cswz = ((t & 7) ^ ((t >> 3) & 7)) << 2;

    const float* pr[4]; const float* pu[4]; const float* pi[4];
    #pragma unroll
    for (int it = 0; it < 4; ++it) {
        int gr = r0 + it * 32 + srow;
        if (gr >= NREV) gr = NREV - 1;        // clamp tail; stores predicated
        pr[it] = rev  + (size_t)gr * DIM + cswz;
        pu[it] = user + (size_t)uidx[gr] * DIM + cswz;
        pi[it] = item + (size_t)iidx[gr] * DIM + cswz;
    }

    f32x4 acc[4][4];
    #pragma unroll
    for (int i = 0; i < 4; ++i)
        #pragma unroll
        for (int j = 0; j < 4; ++j)
            acc[i][j] = (f32x4){0.f, 0.f, 0.f, 0.f};

    const int axor  = (lm & 7) << 4;
    const int koff0 = (lk * 32) ^ axor;

    // issue 6 loads (A:4, B:2) for step s into buffer buf
    auto prefetch = [&](int s, int buf) {
        const int cb = (s & 3) * 32;
        #pragma unroll
        for (int it = 0; it < 4; ++it) {
            const float* src = ((s < 4) ? pr[it] : (s < 8) ? pu[it] : pi[it]) + cb;
            gload_lds16(src, (char*)&Atile[buf][0] + it * 4096 + t * 16);
        }
        #pragma unroll
        for (int it = 0; it < 2; ++it) {
            gload_lds16((const char*)Bw + s * 8192 + it * 4096 + t * 16,
                        (char*)&Btile[buf][0] + it * 4096 + t * 16);
        }
    };

    auto step = [&](int s) {
        const char*           la = (const char*)&Atile[s % 3][0];
        const unsigned short* lb = &Btile[s % 3][0];
        bf16x8 bfrag[4];
        #pragma unroll
        for (int nf = 0; nf < 4; ++nf)
            bfrag[nf] = *reinterpret_cast<const bf16x8*>(
                lb + (((wc * 4 + nf) * 64 + lane) << 3));
        #pragma unroll
        for (int mf = 0; mf < 4; ++mf) {
            int rb = (wr * 64 + mf * 16 + lm) * 128;
            f32x4 f0 = *reinterpret_cast<const f32x4*>(la + rb + koff0);
            f32x4 f1 = *reinterpret_cast<const f32x4*>(la + rb + (koff0 ^ 16));
            bf16x8 af = cvt8(f0, f1);
            #pragma unroll
            for (int nf = 0; nf < 4; ++nf)
                acc[mf][nf] = __builtin_amdgcn_mfma_f32_16x16x32_bf16(
                    af, bfrag[nf], acc[mf][nf], 0, 0, 0);
        }
    };

    // prologue: fill buffers 0,1 (12 loads outstanding)
    prefetch(0, 0);
    prefetch(1, 1);

    #pragma unroll
    for (int s = 0; s < 12; ++s) {
        // wait for step-s tile (oldest 6), keep step-(s+1)'s 6 in flight
        if (s == 11) { asm volatile("s_waitcnt vmcnt(0)" ::: "memory"); }
        else         { asm volatile("s_waitcnt vmcnt(6)" ::: "memory"); }
        __builtin_amdgcn_s_barrier();   // all waves' tile-s data landed;
                                        // buffer (s+2)%3 no longer being read
        asm volatile("" ::: "memory");
        if (s < 10) prefetch(s + 2, (s + 2) % 3);
        step(s);
    }

    // epilogue: ReLU + f32 store (C/D: col=lane&15, row=(lane>>4)*4+j)
    #pragma unroll
    for (int mf = 0; mf < 4; ++mf) {
        #pragma unroll
        for (int j = 0; j < 4; ++j) {
            int row = r0 + wr * 64 + mf * 16 + lk * 4 + j;
            if (row < NREV) {
                float* orow = out + (size_t)row * DIM + wc * 64;
                #pragma unroll
                for (int nf = 0; nf < 4; ++nf)
                    orow[nf * 16 + lm] = fmaxf(acc[mf][nf][j], 0.0f);
            }
        }
    }
}

extern "C" void kernel_launch(void* const* d_in, const int* in_sizes, int n_in,
                              void* d_out, int out_size, void* d_ws, size_t ws_size,
                              hipStream_t stream) {
    const float* rev  = (const float*)d_in[0];
    const float* item = (const float*)d_in[1];
    const float* user = (const float*)d_in[2];
    const int*   uidx = (const int*)d_in[3];
    const int*   iidx = (const int*)d_in[4];
    const float* W    = (const float*)d_in[5];
    unsigned short* Bw = (unsigned short*)d_ws;   // 12*8*64*8*2 = 98304 B
    float* out = (float*)d_out;

    wconv_kernel<<<192, 256, 0, stream>>>(W, Bw);

    int nblocks = (NREV + 127) / 128;   // 3907
    agg_kernel<<<nblocks, 256, 0, stream>>>(rev, item, user, uidx, iidx, Bw, out);
}